// Round 9
// baseline (112.626 us; speedup 1.0000x reference)
//
#include <hip/hip_runtime.h>
#include <hip/hip_fp16.h>
#include <math.h>

#define NROWS 4096
#define LMAX  256
#define KDIM  256
#define NREL  50000
#define NCELL 8                       // row-range cells == XCDs
#define RPC   6250                    // rows per cell (6250*512B fp16 = 3.2MB < 4MiB L2)
#define NBN   64                      // n's per gather block
#define NNB   (NROWS / NBN)           // 64 n-blocks
#define NQ    (NNB * NCELL)           // 512 queues
#define QCAP  2048                    // mean fill ~1028, 12σ headroom

#define TH_BYTES  ((size_t)NREL * KDIM * 2)          // 25,600,000
#define Q_BYTES   ((size_t)NQ * QCAP * 8)            //  8,388,608
#define QC_BYTES  ((size_t)NQ * 4)
#define WS_NEEDED (TH_BYTES + Q_BYTES + QC_BYTES)

typedef float    f32x4 __attribute__((ext_vector_type(4)));
typedef unsigned u32x4 __attribute__((ext_vector_type(4)));

// cell = idx / 6250 for idx < 50000 (magic verified at all k*6250 boundaries)
__device__ __forceinline__ unsigned cell_of(unsigned idx) {
    return (idx * 21475u) >> 27;
}

// ---------- Kernel A: fp32 table -> row-major fp16 tH, XCD-affine by row ---
__global__ __launch_bounds__(256) void convert_kernel(
    const float* __restrict__ table, __half* __restrict__ tH,
    unsigned* __restrict__ qcount)
{
    const int tid = threadIdx.x;
    if (blockIdx.x == 0) {            // zero queue counters for this call
        qcount[tid]       = 0u;
        qcount[tid + 256] = 0u;
    }
    const int cell = blockIdx.x & 7;
    const int rg   = blockIdx.x >> 3;
    const int rloc = rg * 64 + (tid >> 2);
    if (rloc >= RPC) return;
    const int r = cell * RPC + rloc;
    const int q = tid & 3;                        // 64-col quarter

    const float* s = table + (size_t)r * KDIM + q * 64;
    __half*      d = tH    + (size_t)r * KDIM + q * 64;
    #pragma unroll
    for (int i = 0; i < 8; ++i) {
        const f32x4 a = __builtin_nontemporal_load((const f32x4*)s + 2 * i);
        const f32x4 b = __builtin_nontemporal_load((const f32x4*)s + 2 * i + 1);
        __half2 hh[4];
        hh[0] = __floats2half2_rn(a.x, a.y);
        hh[1] = __floats2half2_rn(a.z, a.w);
        hh[2] = __floats2half2_rn(b.x, b.y);
        hh[3] = __floats2half2_rn(b.z, b.w);
        *((uint4*)d + i) = *(const uint4*)hh;
    }
}

// ---------- Kernel B: masked softmax -> bucketed pair records --------------
// record.x = (local_row << 6) | (n & 63), record.y = fp32 weight bits
__global__ __launch_bounds__(256) void pass1_softmax(
    const float* __restrict__ w1,
    const float* __restrict__ w2,
    const int*   __restrict__ neigh_idx,
    const int*   __restrict__ lengths,
    uint2*       __restrict__ queues,
    unsigned*    __restrict__ qcount,
    float*       __restrict__ out)
{
    const int n   = blockIdx.x;
    const int tid = threadIdx.x;

    __shared__ float    s_red[4];
    __shared__ float    s_b;
    __shared__ unsigned l_cnt[8], l_base[8];

    const int len = lengths[n];
    if (tid < 8) l_cnt[tid] = 0u;

    float v = -INFINITY;
    if (tid < len) {
        const float a = __builtin_nontemporal_load(&w1[(size_t)n * LMAX + tid]);
        const float b = __builtin_nontemporal_load(&w2[(size_t)n * LMAX + tid]);
        v = a + b;
    }
    const unsigned idx =
        (unsigned)__builtin_nontemporal_load(&neigh_idx[(size_t)n * LMAX + tid]);

    float m = v;
    #pragma unroll
    for (int off = 32; off >= 1; off >>= 1)
        m = fmaxf(m, __shfl_down(m, off, 64));
    if ((tid & 63) == 0) s_red[tid >> 6] = m;
    __syncthreads();
    if (tid == 0)
        s_b = fmaxf(fmaxf(s_red[0], s_red[1]), fmaxf(s_red[2], s_red[3]));
    __syncthreads();
    m = s_b;

    const float e = (tid < len) ? __expf(v - m) : 0.0f;
    float s = e;
    #pragma unroll
    for (int off = 32; off >= 1; off >>= 1)
        s += __shfl_down(s, off, 64);
    if ((tid & 63) == 0) s_red[tid >> 6] = s;
    __syncthreads();
    if (tid == 0) s_b = s_red[0] + s_red[1] + s_red[2] + s_red[3];
    __syncthreads();

    const float w = e * (1.0f / s_b);

    unsigned cell = 0, rank = 0;
    if (tid < len) {
        cell = cell_of(idx);
        rank = atomicAdd(&l_cnt[cell], 1u);
    }
    __syncthreads();
    if (tid < 8)
        l_base[tid] = atomicAdd(&qcount[(unsigned)(n >> 6) * 8u + tid],
                                l_cnt[tid]);
    __syncthreads();
    if (tid < len) {
        const unsigned pos = l_base[cell] + rank;
        if (pos < QCAP) {
            const unsigned lrow = idx - cell * RPC;
            queues[(size_t)((unsigned)(n >> 6) * 8u + cell) * QCAP + pos] =
                make_uint2((lrow << 6) | (unsigned)(n & 63),
                           __float_as_uint(w));
        }
    }

    if (tid == 0) out[n] = 0.0f;
}

// ---------- Kernel C: row-cell gather, full 512B rows, LDS cand+queue ------
#define CONS(rr, tt, pp) do {                                                \
    const unsigned nloc_ = (rr).x & 63u;                                     \
    const float w_ = ((pp) < count) ? __uint_as_float((rr).y) : 0.0f;        \
    const uint4 cc_ = *(const uint4*)&s_cand[nloc_][c16 * 8];                \
    const __half2* a_ = (const __half2*)&(tt);                               \
    const __half2* b_ = (const __half2*)&cc_;                                \
    const float2 a0_ = __half22float2(a_[0]), b0_ = __half22float2(b_[0]);   \
    const float2 a1_ = __half22float2(a_[1]), b1_ = __half22float2(b_[1]);   \
    const float2 a2_ = __half22float2(a_[2]), b2_ = __half22float2(b_[2]);   \
    const float2 a3_ = __half22float2(a_[3]), b3_ = __half22float2(b_[3]);   \
    float s_ = a0_.x * b0_.x;                                                \
    s_ = fmaf(a0_.y, b0_.y, s_); s_ = fmaf(a1_.x, b1_.x, s_);                \
    s_ = fmaf(a1_.y, b1_.y, s_); s_ = fmaf(a2_.x, b2_.x, s_);                \
    s_ = fmaf(a2_.y, b2_.y, s_); s_ = fmaf(a3_.x, b3_.x, s_);                \
    s_ = fmaf(a3_.y, b3_.y, s_);                                             \
    s_ += __shfl_down(s_, 16, 32); s_ += __shfl_down(s_, 8, 32);             \
    s_ += __shfl_down(s_, 4, 32);  s_ += __shfl_down(s_, 2, 32);             \
    s_ += __shfl_down(s_, 1, 32);                                            \
    if (c16 == 0) atomicAdd(&s_acc[nloc_], w_ * s_);                         \
} while (0)

__global__ __launch_bounds__(256) void gather_kernel(
    const __half*   __restrict__ tH,
    const int*      __restrict__ cand_idx,
    const uint2*    __restrict__ queues,
    const unsigned* __restrict__ qcount,
    float*          __restrict__ out)
{
    const int qid  = blockIdx.x;            // (nb<<3) | cell -> RR over XCDs
    const int cell = qid & 7;
    const int nb   = qid >> 3;
    const int tid  = threadIdx.x;
    const int lane = tid & 63;
    const int wv   = tid >> 6;
    const int h    = lane >> 5;             // which of 2 pairs in this instr
    const int c16  = lane & 31;             // 16B chunk within the 512B row

    __shared__ __align__(16) __half s_cand[NBN][KDIM];   // 32KB
    __shared__ __align__(16) uint2  s_q[QCAP];           // 16KB
    __shared__ float s_acc[NBN];

    const unsigned count = min(qcount[qid], (unsigned)QCAP);

    if (tid < NBN) s_acc[tid] = 0.0f;

    // stage 64 candidate rows (fp16, 512B each) into LDS
    for (int c = tid; c < NBN * 32; c += 256) {
        const int i = c >> 5, off = c & 31;
        const int ci = cand_idx[nb * NBN + i];
        *(uint4*)&s_cand[i][off * 8] =
            *(const uint4*)&tH[(size_t)ci * KDIM + off * 8];
    }
    // stage this block's queue into LDS (2 records per 16B)
    const u32x4* qg = (const u32x4*)(queues + (size_t)qid * QCAP);
    for (int i = tid; 2 * i < (int)count; i += 256) {
        const u32x4 qv = __builtin_nontemporal_load(qg + i);
        *((u32x4*)s_q + i) = qv;
    }
    __syncthreads();

    if (count) {
        const __half* sl = tH + (size_t)cell * RPC * KDIM;   // local slice
        const unsigned cm1 = count - 1;
        for (unsigned b = (unsigned)wv * 8u; b < count; b += 32u) {
            const unsigned p0 = b + h,     p1 = b + 2 + h;
            const unsigned p2 = b + 4 + h, p3 = b + 6 + h;
            const uint2 r0 = s_q[min(p0, cm1)], r1 = s_q[min(p1, cm1)];
            const uint2 r2 = s_q[min(p2, cm1)], r3 = s_q[min(p3, cm1)];
            const uint4 t0 = *(const uint4*)&sl[(size_t)(r0.x >> 6) * KDIM + c16 * 8];
            const uint4 t1 = *(const uint4*)&sl[(size_t)(r1.x >> 6) * KDIM + c16 * 8];
            const uint4 t2 = *(const uint4*)&sl[(size_t)(r2.x >> 6) * KDIM + c16 * 8];
            const uint4 t3 = *(const uint4*)&sl[(size_t)(r3.x >> 6) * KDIM + c16 * 8];
            __builtin_amdgcn_sched_barrier(0);
            CONS(r0, t0, p0); CONS(r1, t1, p1);
            CONS(r2, t2, p2); CONS(r3, t3, p3);
        }
    }
    __syncthreads();
    if (tid < NBN) atomicAdd(&out[nb * NBN + tid], s_acc[tid]);
}

// ---------- Fallback (R1 kernel) if ws too small ---------------------------
__global__ __launch_bounds__(256) void epanre_fallback(
    const float* __restrict__ table,
    const float* __restrict__ w1,
    const float* __restrict__ w2,
    const int*   __restrict__ cand_idx,
    const int*   __restrict__ neigh_idx,
    const int*   __restrict__ lengths,
    float*       __restrict__ out)
{
    const int n   = blockIdx.x;
    const int tid = threadIdx.x;

    __shared__ __align__(16) float s_w[LMAX];
    __shared__ int   s_idx[LMAX];
    __shared__ __align__(16) float s_cand[KDIM];
    __shared__ float s_red[4];
    __shared__ float s_bcast;

    const int len = lengths[n];

    float v = -INFINITY;
    if (tid < len) v = w1[(size_t)n * LMAX + tid] + w2[(size_t)n * LMAX + tid];
    s_idx[tid]  = neigh_idx[(size_t)n * LMAX + tid];
    s_cand[tid] = table[(size_t)cand_idx[n] * KDIM + tid];

    float m = v;
    #pragma unroll
    for (int off = 32; off >= 1; off >>= 1)
        m = fmaxf(m, __shfl_down(m, off, 64));
    if ((tid & 63) == 0) s_red[tid >> 6] = m;
    __syncthreads();
    if (tid == 0)
        s_bcast = fmaxf(fmaxf(s_red[0], s_red[1]), fmaxf(s_red[2], s_red[3]));
    __syncthreads();
    m = s_bcast;

    float e = (tid < len) ? __expf(v - m) : 0.0f;
    float s = e;
    #pragma unroll
    for (int off = 32; off >= 1; off >>= 1)
        s += __shfl_down(s, off, 64);
    if ((tid & 63) == 0) s_red[tid >> 6] = s;
    __syncthreads();
    if (tid == 0) s_bcast = s_red[0] + s_red[1] + s_red[2] + s_red[3];
    __syncthreads();
    const float inv = 1.0f / s_bcast;
    s_w[tid] = e * inv;
    __syncthreads();

    const int g    = tid >> 6;
    const int lane = tid & 63;
    const float4* tab4 = (const float4*)table;
    float4 acc = make_float4(0.f, 0.f, 0.f, 0.f);

    for (int l0 = 0; l0 < len; l0 += 4) {
        const int   l = l0 + g;
        const float w = (l < len) ? s_w[l] : 0.0f;
        const int   idx = s_idx[l];
        const float4 t = tab4[(size_t)idx * (KDIM / 4) + lane];
        acc.x = fmaf(w, t.x, acc.x);
        acc.y = fmaf(w, t.y, acc.y);
        acc.z = fmaf(w, t.z, acc.z);
        acc.w = fmaf(w, t.w, acc.w);
    }

    const float4 c = ((const float4*)s_cand)[lane];
    float partial = acc.x * c.x + acc.y * c.y + acc.z * c.z + acc.w * c.w;
    #pragma unroll
    for (int off = 32; off >= 1; off >>= 1)
        partial += __shfl_down(partial, off, 64);
    if (lane == 0) s_red[g] = partial;
    __syncthreads();
    if (tid == 0) out[n] = s_red[0] + s_red[1] + s_red[2] + s_red[3];
}

extern "C" void kernel_launch(void* const* d_in, const int* in_sizes, int n_in,
                              void* d_out, int out_size, void* d_ws, size_t ws_size,
                              hipStream_t stream) {
    const float* table     = (const float*)d_in[0];
    const float* w1        = (const float*)d_in[1];
    const float* w2        = (const float*)d_in[2];
    const int*   cand_idx  = (const int*)d_in[3];
    const int*   neigh_idx = (const int*)d_in[4];
    const int*   lengths   = (const int*)d_in[5];
    float* out = (float*)d_out;

    if (ws_size < WS_NEEDED) {
        epanre_fallback<<<NROWS, 256, 0, stream>>>(table, w1, w2, cand_idx,
                                                   neigh_idx, lengths, out);
        return;
    }

    __half*   tH     = (__half*)d_ws;
    uint2*    queues = (uint2*)((char*)d_ws + TH_BYTES);
    unsigned* qcount = (unsigned*)((char*)d_ws + TH_BYTES + Q_BYTES);

    const int rgs = (RPC + 63) / 64;                       // 98 row-groups
    convert_kernel<<<rgs * NCELL, 256, 0, stream>>>(table, tH, qcount);
    pass1_softmax<<<NROWS, 256, 0, stream>>>(w1, w2, neigh_idx, lengths,
                                             queues, qcount, out);
    gather_kernel<<<NQ, 256, 0, stream>>>(tH, cand_idx, queues, qcount, out);
}

// Round 10
// 83.149 us; speedup vs baseline: 1.3545x; 1.3545x over previous
//
#include <hip/hip_runtime.h>
#include <hip/hip_fp16.h>
#include <math.h>

#define NROWS 4096
#define LMAX  256
#define KDIM  256
#define NREL  50000
#define NCELL 8                       // row-range cells == XCDs
#define RPC   6250                    // rows per cell (3.2MB fp16 < 4MiB L2)
#define NBN   16                      // n's per gather block
#define NNB   (NROWS / NBN)           // 256 n-blocks
#define NQ    (NNB * NCELL)           // 2048 queues
#define QCAP  512                     // mean fill ~257, +6sigma headroom

#define TH_BYTES  ((size_t)NREL * KDIM * 2)          // 25,600,000
#define Q_BYTES   ((size_t)NQ * QCAP * 8)            //  8,388,608
#define QC_BYTES  ((size_t)NQ * 4)
#define WS_NEEDED (TH_BYTES + Q_BYTES + QC_BYTES)

typedef float    f32x4 __attribute__((ext_vector_type(4)));
typedef unsigned u32x4 __attribute__((ext_vector_type(4)));

// cell = idx / 6250 for idx < 50000
__device__ __forceinline__ unsigned cell_of(unsigned idx) {
    return (idx * 21475u) >> 27;
}

// ---------- Kernel A: fp32 table -> row-major fp16 tH, XCD-affine by row ---
__global__ __launch_bounds__(256) void convert_kernel(
    const float* __restrict__ table, __half* __restrict__ tH,
    unsigned* __restrict__ qcount)
{
    const int tid = threadIdx.x;
    if (blockIdx.x == 0) {            // zero queue counters for this call
        #pragma unroll
        for (int i = 0; i < NQ / 256; ++i)
            qcount[tid + 256 * i] = 0u;
    }
    const int cell = blockIdx.x & 7;
    const int rg   = blockIdx.x >> 3;
    const int rloc = rg * 64 + (tid >> 2);
    if (rloc >= RPC) return;
    const int r = cell * RPC + rloc;
    const int q = tid & 3;                        // 64-col quarter

    const float* s = table + (size_t)r * KDIM + q * 64;
    __half*      d = tH    + (size_t)r * KDIM + q * 64;
    #pragma unroll
    for (int i = 0; i < 8; ++i) {
        const f32x4 a = __builtin_nontemporal_load((const f32x4*)s + 2 * i);
        const f32x4 b = __builtin_nontemporal_load((const f32x4*)s + 2 * i + 1);
        __half2 hh[4];
        hh[0] = __floats2half2_rn(a.x, a.y);
        hh[1] = __floats2half2_rn(a.z, a.w);
        hh[2] = __floats2half2_rn(b.x, b.y);
        hh[3] = __floats2half2_rn(b.z, b.w);
        *((uint4*)d + i) = *(const uint4*)hh;
    }
}

// ---------- Kernel B: masked softmax -> bucketed pair records --------------
// qid = (n>>4)*8 + cell. record.x = (local_row << 6) | (n & 15),
// record.y = fp32 weight bits. One base-atomic per (n, cell) -> the queue is
// a sequence of contiguous same-n runs (avg ~16 entries).
__global__ __launch_bounds__(256) void pass1_softmax(
    const float* __restrict__ w1,
    const float* __restrict__ w2,
    const int*   __restrict__ neigh_idx,
    const int*   __restrict__ lengths,
    uint2*       __restrict__ queues,
    unsigned*    __restrict__ qcount,
    float*       __restrict__ out)
{
    const int n   = blockIdx.x;
    const int tid = threadIdx.x;

    __shared__ float    s_red[4];
    __shared__ float    s_b;
    __shared__ unsigned l_cnt[8], l_base[8];

    const int len = lengths[n];
    if (tid < 8) l_cnt[tid] = 0u;

    float v = -INFINITY;
    if (tid < len) {
        const float a = __builtin_nontemporal_load(&w1[(size_t)n * LMAX + tid]);
        const float b = __builtin_nontemporal_load(&w2[(size_t)n * LMAX + tid]);
        v = a + b;
    }
    const unsigned idx =
        (unsigned)__builtin_nontemporal_load(&neigh_idx[(size_t)n * LMAX + tid]);

    float m = v;
    #pragma unroll
    for (int off = 32; off >= 1; off >>= 1)
        m = fmaxf(m, __shfl_down(m, off, 64));
    if ((tid & 63) == 0) s_red[tid >> 6] = m;
    __syncthreads();
    if (tid == 0)
        s_b = fmaxf(fmaxf(s_red[0], s_red[1]), fmaxf(s_red[2], s_red[3]));
    __syncthreads();
    m = s_b;

    const float e = (tid < len) ? __expf(v - m) : 0.0f;
    float s = e;
    #pragma unroll
    for (int off = 32; off >= 1; off >>= 1)
        s += __shfl_down(s, off, 64);
    if ((tid & 63) == 0) s_red[tid >> 6] = s;
    __syncthreads();
    if (tid == 0) s_b = s_red[0] + s_red[1] + s_red[2] + s_red[3];
    __syncthreads();

    const float w = e * (1.0f / s_b);

    unsigned cell = 0, rank = 0;
    if (tid < len) {
        cell = cell_of(idx);
        rank = atomicAdd(&l_cnt[cell], 1u);
    }
    __syncthreads();
    if (tid < 8)
        l_base[tid] = atomicAdd(&qcount[(unsigned)(n >> 4) * 8u + tid],
                                l_cnt[tid]);
    __syncthreads();
    if (tid < len) {
        const unsigned pos = l_base[cell] + rank;
        if (pos < QCAP) {
            const unsigned lrow = idx - cell * RPC;
            queues[(size_t)((unsigned)(n >> 4) * 8u + cell) * QCAP + pos] =
                make_uint2((lrow << 6) | (unsigned)(n & 15),
                           __float_as_uint(w));
        }
    }

    if (tid == 0) out[n] = 0.0f;
}

// ---------- Kernel C: full-row gather; flush only at run boundaries --------
// One entry = one wave-instruction: 64 lanes x 8B = full 512B fp16 row
// (4 x 128B segments, the minimum). Per-lane partial dot accumulates in a
// register; 6-shuffle reduce + LDS atomic only when the run's n changes.
#define CONSUME(rr, tt, pp) do {                                             \
    const unsigned nl_ = (rr).x & 63u;                                       \
    if (nl_ != cur) {                      /* wave-uniform run boundary */   \
        float red_ = accd;                                                   \
        red_ += __shfl_down(red_, 32, 64); red_ += __shfl_down(red_, 16, 64);\
        red_ += __shfl_down(red_,  8, 64); red_ += __shfl_down(red_,  4, 64);\
        red_ += __shfl_down(red_,  2, 64); red_ += __shfl_down(red_,  1, 64);\
        if (lane == 0) atomicAdd(&s_acc[cur], red_);                         \
        accd = 0.0f; cur = nl_;                                              \
    }                                                                        \
    if ((pp) < end) {                      /* wave-uniform tail guard */     \
        const float w_ = __uint_as_float((rr).y);                            \
        const __half2* a_ = (const __half2*)&(tt);                           \
        const float2 a0_ = __half22float2(a_[0]);                            \
        const float2 a1_ = __half22float2(a_[1]);                            \
        const uint2 cc_ = *(const uint2*)&s_cand[nl_][lane * 4];             \
        const __half2* b_ = (const __half2*)&cc_;                            \
        const float2 b0_ = __half22float2(b_[0]);                            \
        const float2 b1_ = __half22float2(b_[1]);                            \
        float d_ = a0_.x * b0_.x;                                            \
        d_ = fmaf(a0_.y, b0_.y, d_);                                         \
        d_ = fmaf(a1_.x, b1_.x, d_);                                         \
        d_ = fmaf(a1_.y, b1_.y, d_);                                         \
        accd = fmaf(w_, d_, accd);                                           \
    }                                                                        \
} while (0)

__global__ __launch_bounds__(256) void gather_kernel(
    const __half*   __restrict__ tH,
    const int*      __restrict__ cand_idx,
    const uint2*    __restrict__ queues,
    const unsigned* __restrict__ qcount,
    float*          __restrict__ out)
{
    const int qid  = blockIdx.x;            // (nb<<3)|cell -> RR over XCDs
    const int cell = qid & 7;
    const int nb   = qid >> 3;
    const int tid  = threadIdx.x;
    const int lane = tid & 63;
    const int wv   = tid >> 6;

    __shared__ __align__(16) __half s_cand[NBN][KDIM];   // 8KB
    __shared__ __align__(16) uint2  s_q[QCAP];           // 4KB
    __shared__ float s_acc[NBN];

    const unsigned count = min(qcount[qid], (unsigned)QCAP);
    if (tid < NBN) s_acc[tid] = 0.0f;

    // stage 16 candidate rows (fp16, 512B) into LDS: 1024 8B-chunks
    for (int c = tid; c < NBN * 64; c += 256) {
        const int i = c >> 6, off = c & 63;
        const int ci = cand_idx[nb * NBN + i];
        *(uint2*)&s_cand[i][off * 4] =
            *(const uint2*)&tH[(size_t)ci * KDIM + off * 4];
    }
    // stage this block's queue into LDS (2 records per 16B)
    const u32x4* qg = (const u32x4*)(queues + (size_t)qid * QCAP);
    for (int i = tid; 2 * i < (int)count; i += 256) {
        const u32x4 qv = __builtin_nontemporal_load(qg + i);
        *((u32x4*)s_q + i) = qv;
    }
    __syncthreads();

    if (count) {
        const __half* sl = tH + (size_t)cell * RPC * KDIM;   // local slice
        const unsigned per   = (count + 3) >> 2;
        const unsigned start = wv * per;
        const unsigned end   = min(start + per, count);
        if (start < end) {
            const unsigned e1 = end - 1;
            unsigned cur = s_q[start].x & 63u;
            float accd = 0.0f;
            for (unsigned b = start; b < end; b += 4) {
                const unsigned p1 = min(b + 1, e1);
                const unsigned p2 = min(b + 2, e1);
                const unsigned p3 = min(b + 3, e1);
                const uint2 r0 = s_q[b],  r1 = s_q[p1];
                const uint2 r2 = s_q[p2], r3 = s_q[p3];
                const uint2 t0 = *(const uint2*)&sl[(size_t)(r0.x >> 6) * KDIM + lane * 4];
                const uint2 t1 = *(const uint2*)&sl[(size_t)(r1.x >> 6) * KDIM + lane * 4];
                const uint2 t2 = *(const uint2*)&sl[(size_t)(r2.x >> 6) * KDIM + lane * 4];
                const uint2 t3 = *(const uint2*)&sl[(size_t)(r3.x >> 6) * KDIM + lane * 4];
                __builtin_amdgcn_sched_barrier(0);
                CONSUME(r0, t0, b);
                CONSUME(r1, t1, b + 1);
                CONSUME(r2, t2, b + 2);
                CONSUME(r3, t3, b + 3);
            }
            // final flush
            float red = accd;
            red += __shfl_down(red, 32, 64); red += __shfl_down(red, 16, 64);
            red += __shfl_down(red,  8, 64); red += __shfl_down(red,  4, 64);
            red += __shfl_down(red,  2, 64); red += __shfl_down(red,  1, 64);
            if (lane == 0) atomicAdd(&s_acc[cur], red);
        }
    }
    __syncthreads();
    if (tid < NBN) atomicAdd(&out[nb * NBN + tid], s_acc[tid]);
}

// ---------- Fallback (R1 kernel) if ws too small ---------------------------
__global__ __launch_bounds__(256) void epanre_fallback(
    const float* __restrict__ table,
    const float* __restrict__ w1,
    const float* __restrict__ w2,
    const int*   __restrict__ cand_idx,
    const int*   __restrict__ neigh_idx,
    const int*   __restrict__ lengths,
    float*       __restrict__ out)
{
    const int n   = blockIdx.x;
    const int tid = threadIdx.x;

    __shared__ __align__(16) float s_w[LMAX];
    __shared__ int   s_idx[LMAX];
    __shared__ __align__(16) float s_cand[KDIM];
    __shared__ float s_red[4];
    __shared__ float s_bcast;

    const int len = lengths[n];

    float v = -INFINITY;
    if (tid < len) v = w1[(size_t)n * LMAX + tid] + w2[(size_t)n * LMAX + tid];
    s_idx[tid]  = neigh_idx[(size_t)n * LMAX + tid];
    s_cand[tid] = table[(size_t)cand_idx[n] * KDIM + tid];

    float m = v;
    #pragma unroll
    for (int off = 32; off >= 1; off >>= 1)
        m = fmaxf(m, __shfl_down(m, off, 64));
    if ((tid & 63) == 0) s_red[tid >> 6] = m;
    __syncthreads();
    if (tid == 0)
        s_bcast = fmaxf(fmaxf(s_red[0], s_red[1]), fmaxf(s_red[2], s_red[3]));
    __syncthreads();
    m = s_bcast;

    float e = (tid < len) ? __expf(v - m) : 0.0f;
    float s = e;
    #pragma unroll
    for (int off = 32; off >= 1; off >>= 1)
        s += __shfl_down(s, off, 64);
    if ((tid & 63) == 0) s_red[tid >> 6] = s;
    __syncthreads();
    if (tid == 0) s_bcast = s_red[0] + s_red[1] + s_red[2] + s_red[3];
    __syncthreads();
    const float inv = 1.0f / s_bcast;
    s_w[tid] = e * inv;
    __syncthreads();

    const int g    = tid >> 6;
    const int lane = tid & 63;
    const float4* tab4 = (const float4*)table;
    float4 acc = make_float4(0.f, 0.f, 0.f, 0.f);

    for (int l0 = 0; l0 < len; l0 += 4) {
        const int   l = l0 + g;
        const float w = (l < len) ? s_w[l] : 0.0f;
        const int   idx = s_idx[l];
        const float4 t = tab4[(size_t)idx * (KDIM / 4) + lane];
        acc.x = fmaf(w, t.x, acc.x);
        acc.y = fmaf(w, t.y, acc.y);
        acc.z = fmaf(w, t.z, acc.z);
        acc.w = fmaf(w, t.w, acc.w);
    }

    const float4 c = ((const float4*)s_cand)[lane];
    float partial = acc.x * c.x + acc.y * c.y + acc.z * c.z + acc.w * c.w;
    #pragma unroll
    for (int off = 32; off >= 1; off >>= 1)
        partial += __shfl_down(partial, off, 64);
    if (lane == 0) s_red[g] = partial;
    __syncthreads();
    if (tid == 0) out[n] = s_red[0] + s_red[1] + s_red[2] + s_red[3];
}

extern "C" void kernel_launch(void* const* d_in, const int* in_sizes, int n_in,
                              void* d_out, int out_size, void* d_ws, size_t ws_size,
                              hipStream_t stream) {
    const float* table     = (const float*)d_in[0];
    const float* w1        = (const float*)d_in[1];
    const float* w2        = (const float*)d_in[2];
    const int*   cand_idx  = (const int*)d_in[3];
    const int*   neigh_idx = (const int*)d_in[4];
    const int*   lengths   = (const int*)d_in[5];
    float* out = (float*)d_out;

    if (ws_size < WS_NEEDED) {
        epanre_fallback<<<NROWS, 256, 0, stream>>>(table, w1, w2, cand_idx,
                                                   neigh_idx, lengths, out);
        return;
    }

    __half*   tH     = (__half*)d_ws;
    uint2*    queues = (uint2*)((char*)d_ws + TH_BYTES);
    unsigned* qcount = (unsigned*)((char*)d_ws + TH_BYTES + Q_BYTES);

    const int rgs = (RPC + 63) / 64;                       // 98 row-groups
    convert_kernel<<<rgs * NCELL, 256, 0, stream>>>(table, tH, qcount);
    pass1_softmax<<<NROWS, 256, 0, stream>>>(w1, w2, neigh_idx, lengths,
                                             queues, qcount, out);
    gather_kernel<<<NQ, 256, 0, stream>>>(tH, cand_idx, queues, qcount, out);
}

// Round 11
// 53.066 us; speedup vs baseline: 2.1224x; 1.5669x over previous
//
#include <hip/hip_runtime.h>
#include <hip/hip_fp16.h>
#include <math.h>

#define NROWS 4096
#define LMAX  256
#define KDIM  256
#define NREL  50000
#define NCELL 8                       // row-range cells == XCDs
#define RPC   6250                    // rows per cell (3.2MB fp16 < 4MiB L2)
#define NBN   16                      // n's per gather block
#define NNB   (NROWS / NBN)           // 256 n-blocks
#define NQ    (NNB * NCELL)           // 2048 queues
#define QCAP  512                     // mean fill ~257, +6sigma headroom

#define TH_BYTES  ((size_t)NREL * KDIM * 2)          // 25,600,000
#define Q_BYTES   ((size_t)NQ * QCAP * 8)            //  8,388,608
#define QC_BYTES  ((size_t)NQ * 4)
#define WS_NEEDED (TH_BYTES + Q_BYTES + QC_BYTES)

typedef float    f32x4  __attribute__((ext_vector_type(4)));
typedef unsigned u32x4  __attribute__((ext_vector_type(4)));
typedef _Float16 h16x2  __attribute__((ext_vector_type(2)));

__device__ __forceinline__ h16x2 as_h2(unsigned u) {
    union { unsigned u; h16x2 h; } x; x.u = u; return x.h;
}

#if __has_builtin(__builtin_amdgcn_fdot2)
__device__ __forceinline__ float dot4h(uint2 a, uint2 b) {
    float d = __builtin_amdgcn_fdot2(as_h2(a.x), as_h2(b.x), 0.0f, false);
    return  __builtin_amdgcn_fdot2(as_h2(a.y), as_h2(b.y), d,    false);
}
#else
__device__ __forceinline__ float dot4h(uint2 a, uint2 b) {
    const __half2* pa = (const __half2*)&a;
    const __half2* pb = (const __half2*)&b;
    const float2 a0 = __half22float2(pa[0]), b0 = __half22float2(pb[0]);
    const float2 a1 = __half22float2(pa[1]), b1 = __half22float2(pb[1]);
    float d = a0.x * b0.x;
    d = fmaf(a0.y, b0.y, d);
    d = fmaf(a1.x, b1.x, d);
    return fmaf(a1.y, b1.y, d);
}
#endif

// cell = idx / 6250 for idx < 50000
__device__ __forceinline__ unsigned cell_of(unsigned idx) {
    return (idx * 21475u) >> 27;
}

// ---------- Kernel A: fp32 table -> row-major fp16 tH, XCD-affine by row ---
// One wave converts one full row: 64 lanes x 16B f32 load -> 8B fp16 store.
__global__ __launch_bounds__(256) void convert_kernel(
    const float* __restrict__ table, __half* __restrict__ tH,
    unsigned* __restrict__ qcount)
{
    const int tid = threadIdx.x;
    if (blockIdx.x == 0) {            // zero queue counters for this call
        #pragma unroll
        for (int i = 0; i < NQ / 256; ++i)
            qcount[tid + 256 * i] = 0u;
    }
    const int cell = blockIdx.x & 7;
    const int rg   = blockIdx.x >> 3;
    const int rloc = rg * 4 + (tid >> 6);         // 4 rows per block
    if (rloc >= RPC) return;
    const int r    = cell * RPC + rloc;
    const int lane = tid & 63;

    const f32x4 f = __builtin_nontemporal_load(
        (const f32x4*)(table + (size_t)r * KDIM + lane * 4));
    __half2 hh[2];
    hh[0] = __floats2half2_rn(f.x, f.y);
    hh[1] = __floats2half2_rn(f.z, f.w);
    *(uint2*)(tH + (size_t)r * KDIM + lane * 4) = *(const uint2*)hh;
}

// ---------- Kernel B: masked softmax -> bucketed pair records --------------
// qid = (n>>4)*8 + cell. record.x = (local_row << 6) | (n & 15),
// record.y = fp32 weight bits. One base-atomic per (n, cell) -> the queue is
// a sequence of contiguous same-n runs (avg ~16 entries).
__global__ __launch_bounds__(256) void pass1_softmax(
    const float* __restrict__ w1,
    const float* __restrict__ w2,
    const int*   __restrict__ neigh_idx,
    const int*   __restrict__ lengths,
    uint2*       __restrict__ queues,
    unsigned*    __restrict__ qcount,
    float*       __restrict__ out)
{
    const int n   = blockIdx.x;
    const int tid = threadIdx.x;

    __shared__ float    s_red[4];
    __shared__ float    s_b;
    __shared__ unsigned l_cnt[8], l_base[8];

    const int len = lengths[n];
    if (tid < 8) l_cnt[tid] = 0u;

    float v = -INFINITY;
    if (tid < len) {
        const float a = __builtin_nontemporal_load(&w1[(size_t)n * LMAX + tid]);
        const float b = __builtin_nontemporal_load(&w2[(size_t)n * LMAX + tid]);
        v = a + b;
    }
    const unsigned idx =
        (unsigned)__builtin_nontemporal_load(&neigh_idx[(size_t)n * LMAX + tid]);

    float m = v;
    #pragma unroll
    for (int off = 32; off >= 1; off >>= 1)
        m = fmaxf(m, __shfl_down(m, off, 64));
    if ((tid & 63) == 0) s_red[tid >> 6] = m;
    __syncthreads();
    if (tid == 0)
        s_b = fmaxf(fmaxf(s_red[0], s_red[1]), fmaxf(s_red[2], s_red[3]));
    __syncthreads();
    m = s_b;

    const float e = (tid < len) ? __expf(v - m) : 0.0f;
    float s = e;
    #pragma unroll
    for (int off = 32; off >= 1; off >>= 1)
        s += __shfl_down(s, off, 64);
    if ((tid & 63) == 0) s_red[tid >> 6] = s;
    __syncthreads();
    if (tid == 0) s_b = s_red[0] + s_red[1] + s_red[2] + s_red[3];
    __syncthreads();

    const float w = e * (1.0f / s_b);

    unsigned cell = 0, rank = 0;
    if (tid < len) {
        cell = cell_of(idx);
        rank = atomicAdd(&l_cnt[cell], 1u);
    }
    __syncthreads();
    if (tid < 8)
        l_base[tid] = atomicAdd(&qcount[(unsigned)(n >> 4) * 8u + tid],
                                l_cnt[tid]);
    __syncthreads();
    if (tid < len) {
        const unsigned pos = l_base[cell] + rank;
        if (pos < QCAP) {
            const unsigned lrow = idx - cell * RPC;
            queues[(size_t)((unsigned)(n >> 4) * 8u + cell) * QCAP + pos] =
                make_uint2((lrow << 6) | (unsigned)(n & 15),
                           __float_as_uint(w));
        }
    }

    if (tid == 0) out[n] = 0.0f;
}

// ---------- Kernel C: full-row gather; flush only at run boundaries --------
// One entry = one wave-instruction: 64 lanes x 8B = full 512B fp16 row
// (4 x 128B segments). Per-lane dot via v_dot2_f32_f16; 6-shuffle reduce +
// LDS atomic only when the run's n changes.
#define CONSUME(rr, tt, pp) do {                                             \
    const unsigned nl_ = (rr).x & 63u;                                       \
    if (nl_ != cur) {                      /* wave-uniform run boundary */   \
        float red_ = accd;                                                   \
        red_ += __shfl_down(red_, 32, 64); red_ += __shfl_down(red_, 16, 64);\
        red_ += __shfl_down(red_,  8, 64); red_ += __shfl_down(red_,  4, 64);\
        red_ += __shfl_down(red_,  2, 64); red_ += __shfl_down(red_,  1, 64);\
        if (lane == 0) atomicAdd(&s_acc[cur], red_);                         \
        accd = 0.0f; cur = nl_;                                              \
    }                                                                        \
    if ((pp) < end) {                      /* wave-uniform tail guard */     \
        const float w_ = __uint_as_float((rr).y);                            \
        const uint2 cc_ = *(const uint2*)&s_cand[nl_][lane * 4];             \
        accd = fmaf(w_, dot4h((tt), cc_), accd);                             \
    }                                                                        \
} while (0)

__global__ __launch_bounds__(256) void gather_kernel(
    const __half*   __restrict__ tH,
    const int*      __restrict__ cand_idx,
    const uint2*    __restrict__ queues,
    const unsigned* __restrict__ qcount,
    float*          __restrict__ out)
{
    const int qid  = blockIdx.x;            // (nb<<3)|cell -> RR over XCDs
    const int cell = qid & 7;
    const int nb   = qid >> 3;
    const int tid  = threadIdx.x;
    const int lane = tid & 63;
    const int wv   = tid >> 6;

    __shared__ __align__(16) __half s_cand[NBN][KDIM];   // 8KB
    __shared__ __align__(16) uint2  s_q[QCAP];           // 4KB
    __shared__ float s_acc[NBN];

    const unsigned count = min(qcount[qid], (unsigned)QCAP);
    if (tid < NBN) s_acc[tid] = 0.0f;

    // stage 16 candidate rows (fp16, 512B) into LDS: 1024 8B-chunks
    for (int c = tid; c < NBN * 64; c += 256) {
        const int i = c >> 6, off = c & 63;
        const int ci = cand_idx[nb * NBN + i];
        *(uint2*)&s_cand[i][off * 4] =
            *(const uint2*)&tH[(size_t)ci * KDIM + off * 4];
    }
    // stage this block's queue into LDS (2 records per 16B)
    const u32x4* qg = (const u32x4*)(queues + (size_t)qid * QCAP);
    for (int i = tid; 2 * i < (int)count; i += 256) {
        const u32x4 qv = __builtin_nontemporal_load(qg + i);
        *((u32x4*)s_q + i) = qv;
    }
    __syncthreads();

    if (count) {
        const __half* sl = tH + (size_t)cell * RPC * KDIM;   // local slice
        const unsigned per   = (count + 3) >> 2;
        const unsigned start = wv * per;
        const unsigned end   = min(start + per, count);
        if (start < end) {
            const unsigned e1 = end - 1;
            unsigned cur = s_q[start].x & 63u;
            float accd = 0.0f;
            for (unsigned b = start; b < end; b += 4) {
                const unsigned p1 = min(b + 1, e1);
                const unsigned p2 = min(b + 2, e1);
                const unsigned p3 = min(b + 3, e1);
                const uint2 r0 = s_q[b],  r1 = s_q[p1];
                const uint2 r2 = s_q[p2], r3 = s_q[p3];
                const uint2 t0 = *(const uint2*)&sl[(size_t)(r0.x >> 6) * KDIM + lane * 4];
                const uint2 t1 = *(const uint2*)&sl[(size_t)(r1.x >> 6) * KDIM + lane * 4];
                const uint2 t2 = *(const uint2*)&sl[(size_t)(r2.x >> 6) * KDIM + lane * 4];
                const uint2 t3 = *(const uint2*)&sl[(size_t)(r3.x >> 6) * KDIM + lane * 4];
                __builtin_amdgcn_sched_barrier(0);
                CONSUME(r0, t0, b);
                CONSUME(r1, t1, b + 1);
                CONSUME(r2, t2, b + 2);
                CONSUME(r3, t3, b + 3);
            }
            // final flush
            float red = accd;
            red += __shfl_down(red, 32, 64); red += __shfl_down(red, 16, 64);
            red += __shfl_down(red,  8, 64); red += __shfl_down(red,  4, 64);
            red += __shfl_down(red,  2, 64); red += __shfl_down(red,  1, 64);
            if (lane == 0) atomicAdd(&s_acc[cur], red);
        }
    }
    __syncthreads();
    if (tid < NBN) atomicAdd(&out[nb * NBN + tid], s_acc[tid]);
}

// ---------- Fallback (R1 kernel) if ws too small ---------------------------
__global__ __launch_bounds__(256) void epanre_fallback(
    const float* __restrict__ table,
    const float* __restrict__ w1,
    const float* __restrict__ w2,
    const int*   __restrict__ cand_idx,
    const int*   __restrict__ neigh_idx,
    const int*   __restrict__ lengths,
    float*       __restrict__ out)
{
    const int n   = blockIdx.x;
    const int tid = threadIdx.x;

    __shared__ __align__(16) float s_w[LMAX];
    __shared__ int   s_idx[LMAX];
    __shared__ __align__(16) float s_cand[KDIM];
    __shared__ float s_red[4];
    __shared__ float s_bcast;

    const int len = lengths[n];

    float v = -INFINITY;
    if (tid < len) v = w1[(size_t)n * LMAX + tid] + w2[(size_t)n * LMAX + tid];
    s_idx[tid]  = neigh_idx[(size_t)n * LMAX + tid];
    s_cand[tid] = table[(size_t)cand_idx[n] * KDIM + tid];

    float m = v;
    #pragma unroll
    for (int off = 32; off >= 1; off >>= 1)
        m = fmaxf(m, __shfl_down(m, off, 64));
    if ((tid & 63) == 0) s_red[tid >> 6] = m;
    __syncthreads();
    if (tid == 0)
        s_bcast = fmaxf(fmaxf(s_red[0], s_red[1]), fmaxf(s_red[2], s_red[3]));
    __syncthreads();
    m = s_bcast;

    float e = (tid < len) ? __expf(v - m) : 0.0f;
    float s = e;
    #pragma unroll
    for (int off = 32; off >= 1; off >>= 1)
        s += __shfl_down(s, off, 64);
    if ((tid & 63) == 0) s_red[tid >> 6] = s;
    __syncthreads();
    if (tid == 0) s_bcast = s_red[0] + s_red[1] + s_red[2] + s_red[3];
    __syncthreads();
    const float inv = 1.0f / s_bcast;
    s_w[tid] = e * inv;
    __syncthreads();

    const int g    = tid >> 6;
    const int lane = tid & 63;
    const float4* tab4 = (const float4*)table;
    float4 acc = make_float4(0.f, 0.f, 0.f, 0.f);

    for (int l0 = 0; l0 < len; l0 += 4) {
        const int   l = l0 + g;
        const float w = (l < len) ? s_w[l] : 0.0f;
        const int   idx = s_idx[l];
        const float4 t = tab4[(size_t)idx * (KDIM / 4) + lane];
        acc.x = fmaf(w, t.x, acc.x);
        acc.y = fmaf(w, t.y, acc.y);
        acc.z = fmaf(w, t.z, acc.z);
        acc.w = fmaf(w, t.w, acc.w);
    }

    const float4 c = ((const float4*)s_cand)[lane];
    float partial = acc.x * c.x + acc.y * c.y + acc.z * c.z + acc.w * c.w;
    #pragma unroll
    for (int off = 32; off >= 1; off >>= 1)
        partial += __shfl_down(partial, off, 64);
    if (lane == 0) s_red[g] = partial;
    __syncthreads();
    if (tid == 0) out[n] = s_red[0] + s_red[1] + s_red[2] + s_red[3];
}

extern "C" void kernel_launch(void* const* d_in, const int* in_sizes, int n_in,
                              void* d_out, int out_size, void* d_ws, size_t ws_size,
                              hipStream_t stream) {
    const float* table     = (const float*)d_in[0];
    const float* w1        = (const float*)d_in[1];
    const float* w2        = (const float*)d_in[2];
    const int*   cand_idx  = (const int*)d_in[3];
    const int*   neigh_idx = (const int*)d_in[4];
    const int*   lengths   = (const int*)d_in[5];
    float* out = (float*)d_out;

    if (ws_size < WS_NEEDED) {
        epanre_fallback<<<NROWS, 256, 0, stream>>>(table, w1, w2, cand_idx,
                                                   neigh_idx, lengths, out);
        return;
    }

    __half*   tH     = (__half*)d_ws;
    uint2*    queues = (uint2*)((char*)d_ws + TH_BYTES);
    unsigned* qcount = (unsigned*)((char*)d_ws + TH_BYTES + Q_BYTES);

    const int rgs = (RPC + 3) / 4;                         // 1563 row-groups
    convert_kernel<<<rgs * NCELL, 256, 0, stream>>>(table, tH, qcount);
    pass1_softmax<<<NROWS, 256, 0, stream>>>(w1, w2, neigh_idx, lengths,
                                             queues, qcount, out);
    gather_kernel<<<NQ, 256, 0, stream>>>(tH, cand_idx, queues, qcount, out);
}

// Round 12
// 52.695 us; speedup vs baseline: 2.1373x; 1.0070x over previous
//
#include <hip/hip_runtime.h>
#include <hip/hip_fp16.h>
#include <math.h>

#define NROWS 4096
#define LMAX  256
#define KDIM  256
#define NREL  50000
#define NCELL 8                       // row-range cells == XCDs
#define RPC   6250                    // rows per cell (3.2MB fp16 < 4MiB L2)
#define NBN   16                      // n's per gather block
#define NNB   (NROWS / NBN)           // 256 n-blocks
#define NQ    (NNB * NCELL)           // 2048 queues
#define QCAP  512                     // mean fill ~257, +6sigma headroom
#define SMB   (NROWS / 4)             // softmax blocks (4 waves = 4 n's each)

#define TH_BYTES  ((size_t)NREL * KDIM * 2)          // 25,600,000
#define Q_BYTES   ((size_t)NQ * QCAP * 8)            //  8,388,608
#define QC_BYTES  ((size_t)NQ * 4)
#define WS_NEEDED (TH_BYTES + Q_BYTES + QC_BYTES)

typedef float    f32x4  __attribute__((ext_vector_type(4)));
typedef unsigned u32x4  __attribute__((ext_vector_type(4)));
typedef _Float16 h16x2  __attribute__((ext_vector_type(2)));

__device__ __forceinline__ h16x2 as_h2(unsigned u) {
    union { unsigned u; h16x2 h; } x; x.u = u; return x.h;
}

#if __has_builtin(__builtin_amdgcn_fdot2)
__device__ __forceinline__ float dot4h(uint2 a, uint2 b) {
    float d = __builtin_amdgcn_fdot2(as_h2(a.x), as_h2(b.x), 0.0f, false);
    return  __builtin_amdgcn_fdot2(as_h2(a.y), as_h2(b.y), d,    false);
}
#else
__device__ __forceinline__ float dot4h(uint2 a, uint2 b) {
    const __half2* pa = (const __half2*)&a;
    const __half2* pb = (const __half2*)&b;
    const float2 a0 = __half22float2(pa[0]), b0 = __half22float2(pb[0]);
    const float2 a1 = __half22float2(pa[1]), b1 = __half22float2(pb[1]);
    float d = a0.x * b0.x;
    d = fmaf(a0.y, b0.y, d);
    d = fmaf(a1.x, b1.x, d);
    return fmaf(a1.y, b1.y, d);
}
#endif

// cell = idx / 6250 for idx < 50000
__device__ __forceinline__ unsigned cell_of(unsigned idx) {
    return (idx * 21475u) >> 27;
}

// ---------- Kernel A (fused prep): softmax blocks + convert blocks ---------
// Blocks [0, SMB): wave-per-n masked softmax -> bucketed queue records.
// Blocks [SMB, ...): fp32 table -> row-major fp16 tH (XCD-affine by row).
// Softmax first so its latency-bound blocks overlap convert's streaming.
// qcount is zeroed by hipMemsetAsync before this kernel.
__global__ __launch_bounds__(256) void fused_prep(
    const float* __restrict__ table,
    const float* __restrict__ w1,
    const float* __restrict__ w2,
    const int*   __restrict__ neigh_idx,
    const int*   __restrict__ lengths,
    __half*      __restrict__ tH,
    uint2*       __restrict__ queues,
    unsigned*    __restrict__ qcount,
    float*       __restrict__ out)
{
    const int tid  = threadIdx.x;
    const int lane = tid & 63;
    const int wv   = tid >> 6;

    if (blockIdx.x < SMB) {
        // ---- wave-per-n softmax; no __syncthreads anywhere ----
        const int n   = blockIdx.x * 4 + wv;
        const int len = lengths[n];

        __shared__ unsigned l_cnt[4][8], l_base[4][8];

        const f32x4 a = __builtin_nontemporal_load(
            (const f32x4*)(w1 + (size_t)n * LMAX) + lane);
        const f32x4 b = __builtin_nontemporal_load(
            (const f32x4*)(w2 + (size_t)n * LMAX) + lane);
        const u32x4 ii = __builtin_nontemporal_load(
            (const u32x4*)(neigh_idx + (size_t)n * LMAX) + lane);

        float v[4];
        #pragma unroll
        for (int j = 0; j < 4; ++j)
            v[j] = (lane * 4 + j < len) ? (a[j] + b[j]) : -INFINITY;

        float m = fmaxf(fmaxf(v[0], v[1]), fmaxf(v[2], v[3]));
        #pragma unroll
        for (int off = 32; off >= 1; off >>= 1)
            m = fmaxf(m, __shfl_xor(m, off, 64));

        float e[4];
        float s = 0.0f;
        #pragma unroll
        for (int j = 0; j < 4; ++j) {
            e[j] = (lane * 4 + j < len) ? __expf(v[j] - m) : 0.0f;
            s += e[j];
        }
        #pragma unroll
        for (int off = 32; off >= 1; off >>= 1)
            s += __shfl_xor(s, off, 64);
        const float inv = 1.0f / s;

        if (lane < 8) l_cnt[wv][lane] = 0u;
        // same-wave LDS ordering: atomics below issue after the zeroing

        unsigned cc[4] = {0, 0, 0, 0}, rk[4] = {0, 0, 0, 0};
        #pragma unroll
        for (int j = 0; j < 4; ++j) {
            if (lane * 4 + j < len) {
                cc[j] = cell_of(ii[j]);
                rk[j] = atomicAdd(&l_cnt[wv][cc[j]], 1u);
            }
        }
        if (lane < 8)
            l_base[wv][lane] = atomicAdd(&qcount[(unsigned)(n >> 4) * 8u + lane],
                                         l_cnt[wv][lane]);
        #pragma unroll
        for (int j = 0; j < 4; ++j) {
            if (lane * 4 + j < len) {
                const unsigned pos = l_base[wv][cc[j]] + rk[j];
                if (pos < QCAP) {
                    const unsigned lrow = ii[j] - cc[j] * RPC;
                    queues[(size_t)((unsigned)(n >> 4) * 8u + cc[j]) * QCAP + pos] =
                        make_uint2((lrow << 6) | (unsigned)(n & 15),
                                   __float_as_uint(e[j] * inv));
                }
            }
        }
        if (lane == 0) out[n] = 0.0f;
    } else {
        // ---- convert: one wave per row, 4 rows per block ----
        const int bb   = blockIdx.x - SMB;
        const int cell = bb & 7;
        const int rg   = bb >> 3;
        const int rloc = rg * 4 + wv;
        if (rloc >= RPC) return;
        const int r = cell * RPC + rloc;

        const f32x4 f = __builtin_nontemporal_load(
            (const f32x4*)(table + (size_t)r * KDIM + lane * 4));
        __half2 hh[2];
        hh[0] = __floats2half2_rn(f.x, f.y);
        hh[1] = __floats2half2_rn(f.z, f.w);
        *(uint2*)(tH + (size_t)r * KDIM + lane * 4) = *(const uint2*)hh;
    }
}

// ---------- Kernel C: full-row gather; flush only at run boundaries --------
// One entry = one wave-instruction: 64 lanes x 8B = full 512B fp16 row.
// Per-lane dot via v_dot2_f32_f16; 6-shuffle reduce + LDS atomic only when
// the run's n changes (one queue reservation per (n,cell) -> contiguous runs).
#define CONSUME(rr, tt, pp) do {                                             \
    const unsigned nl_ = (rr).x & 63u;                                       \
    if (nl_ != cur) {                      /* wave-uniform run boundary */   \
        float red_ = accd;                                                   \
        red_ += __shfl_down(red_, 32, 64); red_ += __shfl_down(red_, 16, 64);\
        red_ += __shfl_down(red_,  8, 64); red_ += __shfl_down(red_,  4, 64);\
        red_ += __shfl_down(red_,  2, 64); red_ += __shfl_down(red_,  1, 64);\
        if (lane == 0) atomicAdd(&s_acc[cur], red_);                         \
        accd = 0.0f; cur = nl_;                                              \
    }                                                                        \
    if ((pp) < end) {                      /* wave-uniform tail guard */     \
        const float w_ = __uint_as_float((rr).y);                            \
        const uint2 cc_ = *(const uint2*)&s_cand[nl_][lane * 4];             \
        accd = fmaf(w_, dot4h((tt), cc_), accd);                             \
    }                                                                        \
} while (0)

__global__ __launch_bounds__(256) void gather_kernel(
    const __half*   __restrict__ tH,
    const int*      __restrict__ cand_idx,
    const uint2*    __restrict__ queues,
    const unsigned* __restrict__ qcount,
    float*          __restrict__ out)
{
    const int qid  = blockIdx.x;            // (nb<<3)|cell -> RR over XCDs
    const int cell = qid & 7;
    const int nb   = qid >> 3;
    const int tid  = threadIdx.x;
    const int lane = tid & 63;
    const int wv   = tid >> 6;

    __shared__ __align__(16) __half s_cand[NBN][KDIM];   // 8KB
    __shared__ __align__(16) uint2  s_q[QCAP];           // 4KB
    __shared__ float s_acc[NBN];

    const unsigned count = min(qcount[qid], (unsigned)QCAP);
    if (tid < NBN) s_acc[tid] = 0.0f;

    // stage 16 candidate rows (fp16, 512B) into LDS: 1024 8B-chunks
    for (int c = tid; c < NBN * 64; c += 256) {
        const int i = c >> 6, off = c & 63;
        const int ci = cand_idx[nb * NBN + i];
        *(uint2*)&s_cand[i][off * 4] =
            *(const uint2*)&tH[(size_t)ci * KDIM + off * 4];
    }
    // stage this block's queue into LDS (2 records per 16B)
    const u32x4* qg = (const u32x4*)(queues + (size_t)qid * QCAP);
    for (int i = tid; 2 * i < (int)count; i += 256) {
        const u32x4 qv = __builtin_nontemporal_load(qg + i);
        *((u32x4*)s_q + i) = qv;
    }
    __syncthreads();

    if (count) {
        const __half* sl = tH + (size_t)cell * RPC * KDIM;   // local slice
        const unsigned per   = (count + 3) >> 2;
        const unsigned start = wv * per;
        const unsigned end   = min(start + per, count);
        if (start < end) {
            const unsigned e1 = end - 1;
            unsigned cur = s_q[start].x & 63u;
            float accd = 0.0f;
            for (unsigned b = start; b < end; b += 4) {
                const unsigned p1 = min(b + 1, e1);
                const unsigned p2 = min(b + 2, e1);
                const unsigned p3 = min(b + 3, e1);
                const uint2 r0 = s_q[b],  r1 = s_q[p1];
                const uint2 r2 = s_q[p2], r3 = s_q[p3];
                const uint2 t0 = *(const uint2*)&sl[(size_t)(r0.x >> 6) * KDIM + lane * 4];
                const uint2 t1 = *(const uint2*)&sl[(size_t)(r1.x >> 6) * KDIM + lane * 4];
                const uint2 t2 = *(const uint2*)&sl[(size_t)(r2.x >> 6) * KDIM + lane * 4];
                const uint2 t3 = *(const uint2*)&sl[(size_t)(r3.x >> 6) * KDIM + lane * 4];
                __builtin_amdgcn_sched_barrier(0);
                CONSUME(r0, t0, b);
                CONSUME(r1, t1, b + 1);
                CONSUME(r2, t2, b + 2);
                CONSUME(r3, t3, b + 3);
            }
            // final flush
            float red = accd;
            red += __shfl_down(red, 32, 64); red += __shfl_down(red, 16, 64);
            red += __shfl_down(red,  8, 64); red += __shfl_down(red,  4, 64);
            red += __shfl_down(red,  2, 64); red += __shfl_down(red,  1, 64);
            if (lane == 0) atomicAdd(&s_acc[cur], red);
        }
    }
    __syncthreads();
    if (tid < NBN) atomicAdd(&out[nb * NBN + tid], s_acc[tid]);
}

// ---------- Fallback (R1 kernel) if ws too small ---------------------------
__global__ __launch_bounds__(256) void epanre_fallback(
    const float* __restrict__ table,
    const float* __restrict__ w1,
    const float* __restrict__ w2,
    const int*   __restrict__ cand_idx,
    const int*   __restrict__ neigh_idx,
    const int*   __restrict__ lengths,
    float*       __restrict__ out)
{
    const int n   = blockIdx.x;
    const int tid = threadIdx.x;

    __shared__ __align__(16) float s_w[LMAX];
    __shared__ int   s_idx[LMAX];
    __shared__ __align__(16) float s_cand[KDIM];
    __shared__ float s_red[4];
    __shared__ float s_bcast;

    const int len = lengths[n];

    float v = -INFINITY;
    if (tid < len) v = w1[(size_t)n * LMAX + tid] + w2[(size_t)n * LMAX + tid];
    s_idx[tid]  = neigh_idx[(size_t)n * LMAX + tid];
    s_cand[tid] = table[(size_t)cand_idx[n] * KDIM + tid];

    float m = v;
    #pragma unroll
    for (int off = 32; off >= 1; off >>= 1)
        m = fmaxf(m, __shfl_down(m, off, 64));
    if ((tid & 63) == 0) s_red[tid >> 6] = m;
    __syncthreads();
    if (tid == 0)
        s_bcast = fmaxf(fmaxf(s_red[0], s_red[1]), fmaxf(s_red[2], s_red[3]));
    __syncthreads();
    m = s_bcast;

    float e = (tid < len) ? __expf(v - m) : 0.0f;
    float s = e;
    #pragma unroll
    for (int off = 32; off >= 1; off >>= 1)
        s += __shfl_down(s, off, 64);
    if ((tid & 63) == 0) s_red[tid >> 6] = s;
    __syncthreads();
    if (tid == 0) s_bcast = s_red[0] + s_red[1] + s_red[2] + s_red[3];
    __syncthreads();
    const float inv = 1.0f / s_bcast;
    s_w[tid] = e * inv;
    __syncthreads();

    const int g    = tid >> 6;
    const int lane = tid & 63;
    const float4* tab4 = (const float4*)table;
    float4 acc = make_float4(0.f, 0.f, 0.f, 0.f);

    for (int l0 = 0; l0 < len; l0 += 4) {
        const int   l = l0 + g;
        const float w = (l < len) ? s_w[l] : 0.0f;
        const int   idx = s_idx[l];
        const float4 t = tab4[(size_t)idx * (KDIM / 4) + lane];
        acc.x = fmaf(w, t.x, acc.x);
        acc.y = fmaf(w, t.y, acc.y);
        acc.z = fmaf(w, t.z, acc.z);
        acc.w = fmaf(w, t.w, acc.w);
    }

    const float4 c = ((const float4*)s_cand)[lane];
    float partial = acc.x * c.x + acc.y * c.y + acc.z * c.z + acc.w * c.w;
    #pragma unroll
    for (int off = 32; off >= 1; off >>= 1)
        partial += __shfl_down(partial, off, 64);
    if (lane == 0) s_red[g] = partial;
    __syncthreads();
    if (tid == 0) out[n] = s_red[0] + s_red[1] + s_red[2] + s_red[3];
}

extern "C" void kernel_launch(void* const* d_in, const int* in_sizes, int n_in,
                              void* d_out, int out_size, void* d_ws, size_t ws_size,
                              hipStream_t stream) {
    const float* table     = (const float*)d_in[0];
    const float* w1        = (const float*)d_in[1];
    const float* w2        = (const float*)d_in[2];
    const int*   cand_idx  = (const int*)d_in[3];
    const int*   neigh_idx = (const int*)d_in[4];
    const int*   lengths   = (const int*)d_in[5];
    float* out = (float*)d_out;

    if (ws_size < WS_NEEDED) {
        epanre_fallback<<<NROWS, 256, 0, stream>>>(table, w1, w2, cand_idx,
                                                   neigh_idx, lengths, out);
        return;
    }

    __half*   tH     = (__half*)d_ws;
    uint2*    queues = (uint2*)((char*)d_ws + TH_BYTES);
    unsigned* qcount = (unsigned*)((char*)d_ws + TH_BYTES + Q_BYTES);

    hipMemsetAsync(qcount, 0, QC_BYTES, stream);

    const int rgs = (RPC + 3) / 4;                         // 1563 row-groups
    fused_prep<<<SMB + rgs * NCELL, 256, 0, stream>>>(table, w1, w2,
                                                      neigh_idx, lengths,
                                                      tH, queues, qcount, out);
    gather_kernel<<<NQ, 256, 0, stream>>>(tH, cand_idx, queues, qcount, out);
}